// Round 1
// baseline (158.862 us; speedup 1.0000x reference)
//
#include <hip/hip_runtime.h>

// ---------------------------------------------------------------------------
// SocialPooling: pooled = per-person 8x8-grid scatter-add of neighbor hiddens,
// out = relu(pooled @ W + b).  M=B=4096, K=4096, N=1024.
// Strategy: fp32-exact pooling -> bf16 pooled (ws), W -> Wt bf16 (ws),
// MFMA bf16 GEMM with fused bias+relu.
// ---------------------------------------------------------------------------

#define BM 128
#define BN 64
#define BK 64

typedef short short8 __attribute__((ext_vector_type(8)));
typedef float floatx4 __attribute__((ext_vector_type(4)));

__device__ inline short f2bf(float x) {
    union { float f; unsigned u; } v; v.f = x;
    unsigned r = v.u + 0x7fffu + ((v.u >> 16) & 1u);   // round-to-nearest-even
    return (short)(r >> 16);
}

__device__ inline void gload_lds16(const void* g, void* l) {
    __builtin_amdgcn_global_load_lds(
        (const __attribute__((address_space(1))) void*)g,
        (__attribute__((address_space(3))) void*)l,
        16, 0, 0);
}

// ---------------------------------------------------------------------------
// Kernel 1: pooling. One 64-lane wave per person; thread = hidden dim.
// Cell math is bit-identical to the jnp reference: (x/2)*8 == x*4 exactly.
// ---------------------------------------------------------------------------
__global__ __launch_bounds__(64) void pool_kernel(
    const float* __restrict__ h,     // (B, 64)
    const float* __restrict__ pos,   // (B, 2)
    short* __restrict__ pooled,      // (B, 4096) bf16
    int P)
{
    __shared__ float acc[64 * 64];    // [cell][dim]
    __shared__ float px[64], py[64];
    __shared__ int   cellIdx[64];

    const int d = threadIdx.x;              // dim 0..63
    const int s = blockIdx.x / P;
    const int i = blockIdx.x - s * P;
    const int base = s * P;

    #pragma unroll
    for (int c = 0; c < 64; ++c) acc[c * 64 + d] = 0.f;

    if (d < P) {
        px[d] = pos[(size_t)(base + d) * 2 + 0];
        py[d] = pos[(size_t)(base + d) * 2 + 1];
    }
    __syncthreads();

    const float tlx = px[i] - 1.0f;
    const float tly = py[i] + 1.0f;
    const float brx = px[i] + 1.0f;
    const float bry = py[i] - 1.0f;

    if (d < P) {
        const float ox = px[d], oy = py[d];
        int cell = -1;
        if (ox < brx && ox > tlx && oy < tly && oy > bry && d != i) {
            int cx = (int)floorf((ox - tlx) * 4.0f);
            int cy = (int)floorf((tly - oy) * 4.0f);
            cell = cx + cy * 8;
        }
        cellIdx[d] = cell;
    }
    __syncthreads();

    for (int j = 0; j < P; ++j) {
        int c = cellIdx[j];
        if (c >= 0) acc[c * 64 + d] += h[(size_t)(base + j) * 64 + d];
    }

    const size_t row = (size_t)(base + i) * 4096;
    #pragma unroll
    for (int c = 0; c < 64; ++c)
        pooled[row + c * 64 + d] = f2bf(acc[c * 64 + d]);
}

// ---------------------------------------------------------------------------
// Kernel 2: W (K x N fp32) -> Wt (N x K bf16), LDS-tiled transpose.
// ---------------------------------------------------------------------------
__global__ __launch_bounds__(256) void castWt_kernel(
    const float* __restrict__ W, short* __restrict__ Wt, int K, int N)
{
    __shared__ float tile[32][33];
    const int tx = threadIdx.x;   // 0..31
    const int ty = threadIdx.y;   // 0..7
    const int k0 = blockIdx.x * 32;
    const int n0 = blockIdx.y * 32;

    #pragma unroll
    for (int i = 0; i < 32; i += 8)
        tile[ty + i][tx] = W[(size_t)(k0 + ty + i) * N + n0 + tx];
    __syncthreads();
    #pragma unroll
    for (int i = 0; i < 32; i += 8)
        Wt[(size_t)(n0 + ty + i) * K + k0 + tx] = f2bf(tile[tx][ty + i]);
}

// ---------------------------------------------------------------------------
// Kernel 3: C = relu(A @ Bt^T + bias).  A: MxK bf16, Bt: NxK bf16.
// 128x64 block tile, BK=64, 4 waves (2x2), each wave 64x32 (4x2 MFMA tiles).
// global_load_lds(16B) staging; XOR swizzle applied on the GLOBAL address so
// the lane-linear LDS layout is bank-conflict-free on ds_read_b128.
// ---------------------------------------------------------------------------
__global__ __launch_bounds__(256) void gemm_bias_relu(
    const short* __restrict__ A,
    const short* __restrict__ Bt,
    const float* __restrict__ bias,
    float* __restrict__ out,
    int M, int N, int K)
{
    __shared__ __align__(16) short As[BM * BK];  // 16 KB
    __shared__ __align__(16) short Bs[BN * BK];  //  8 KB

    const int tid  = threadIdx.x;
    const int lane = tid & 63;
    const int wave = tid >> 6;
    const int wr = wave >> 1;          // wave row (m): 0..1
    const int wc = wave & 1;           // wave col (n): 0..1
    const int q  = lane >> 4;          // quad 0..3
    const int ml = lane & 15;
    const int m0 = blockIdx.y * BM;
    const int n0 = blockIdx.x * BN;

    const int rsub = lane >> 3;                   // 0..7 (row within 8-row chunk)
    const int swz  = (lane & 7) ^ rsub;           // global granule permutation

    // per-thread staging pointers (advanced by BK shorts per iteration)
    const short* ag[4];
    const short* bg[2];
    #pragma unroll
    for (int c = 0; c < 4; ++c)
        ag[c] = A + (size_t)(m0 + (c * 4 + wave) * 8 + rsub) * K + swz * 8;
    #pragma unroll
    for (int c = 0; c < 2; ++c)
        bg[c] = Bt + (size_t)(n0 + (c * 4 + wave) * 8 + rsub) * K + swz * 8;

    floatx4 acc[4][2];
    #pragma unroll
    for (int i = 0; i < 4; ++i)
        #pragma unroll
        for (int j = 0; j < 2; ++j)
            acc[i][j] = (floatx4){0.f, 0.f, 0.f, 0.f};

    for (int kb = 0; kb < K; kb += BK) {
        if (kb) __syncthreads();               // protect LDS from overwrite
        #pragma unroll
        for (int c = 0; c < 4; ++c) {
            gload_lds16(ag[c], &As[(c * 4 + wave) * 512]);
            ag[c] += BK;
        }
        #pragma unroll
        for (int c = 0; c < 2; ++c) {
            gload_lds16(bg[c], &Bs[(c * 4 + wave) * 512]);
            bg[c] += BK;
        }
        __syncthreads();                       // compiler drains vmcnt before barrier

        #pragma unroll
        for (int t = 0; t < 2; ++t) {
            short8 af[4], bf[2];
            const int gx = ((4 * t + q) ^ (ml & 7)) * 8;  // swizzled granule, in shorts
            #pragma unroll
            for (int i = 0; i < 4; ++i)
                af[i] = *(const short8*)&As[(wr * 64 + i * 16 + ml) * 64 + gx];
            #pragma unroll
            for (int j = 0; j < 2; ++j)
                bf[j] = *(const short8*)&Bs[(wc * 32 + j * 16 + ml) * 64 + gx];
            #pragma unroll
            for (int i = 0; i < 4; ++i)
                #pragma unroll
                for (int j = 0; j < 2; ++j)
                    acc[i][j] = __builtin_amdgcn_mfma_f32_16x16x32_bf16(
                        af[i], bf[j], acc[i][j], 0, 0, 0);
        }
    }

    // epilogue: bias + relu, fp32 store.  C/D layout: col=lane&15, row=q*4+reg.
    #pragma unroll
    for (int j = 0; j < 2; ++j) {
        const int gn = n0 + wc * 32 + j * 16 + ml;
        const float bv = bias[gn];
        #pragma unroll
        for (int i = 0; i < 4; ++i) {
            const int gm = m0 + wr * 64 + i * 16 + q * 4;
            #pragma unroll
            for (int r = 0; r < 4; ++r) {
                float v = acc[i][j][r] + bv;
                out[(size_t)(gm + r) * N + gn] = v > 0.f ? v : 0.f;
            }
        }
    }
}

// ---------------------------------------------------------------------------
extern "C" void kernel_launch(void* const* d_in, const int* in_sizes, int n_in,
                              void* d_out, int out_size, void* d_ws, size_t ws_size,
                              hipStream_t stream) {
    const float* h    = (const float*)d_in[0];   // (1, B, 64) f32
    const float* pos  = (const float*)d_in[2];   // (B, 2)     f32
    const float* W    = (const float*)d_in[4];   // (K, N)     f32
    const float* bias = (const float*)d_in[5];   // (N,)       f32

    const int B = in_sizes[0] / 64;       // 4096
    const int S = in_sizes[1] / 2;        // 64
    const int P = B / S;                  // 64
    const int N = in_sizes[5];            // 1024
    const int K = 64 * 64;                // GRID^2 * H_DIM = 4096

    short* pooled = (short*)d_ws;                  // B*K bf16 = 32 MB
    short* Wt     = pooled + (size_t)B * K;        // N*K bf16 =  8 MB
    float* out    = (float*)d_out;

    pool_kernel<<<B, 64, 0, stream>>>(h, pos, pooled, P);
    castWt_kernel<<<dim3(K / 32, N / 32), dim3(32, 8), 0, stream>>>(W, Wt, K, N);
    gemm_bias_relu<<<dim3(N / BN, B / BM), 256, 0, stream>>>(pooled, Wt, bias, out, B, N, K);
}

// Round 2
// 141.318 us; speedup vs baseline: 1.1241x; 1.1241x over previous
//
#include <hip/hip_runtime.h>

// ---------------------------------------------------------------------------
// SocialPooling: pooled = per-person 8x8-grid scatter-add of neighbor hiddens,
// out = relu(pooled @ W + b).  M=B=4096, K=4096, N=1024.
// R1: pool via per-cell bitmasks (LDS atomicOr + mask-walk), vectorized
// transpose, GEMM BK=128 (half the barrier drains).
// ---------------------------------------------------------------------------

#define BM 128
#define BN 64
#define BK 128   // shorts (bf16) per K-block

typedef short short8 __attribute__((ext_vector_type(8)));
typedef short short4v __attribute__((ext_vector_type(4)));
typedef float floatx4 __attribute__((ext_vector_type(4)));

__device__ inline short f2bf(float x) {
    union { float f; unsigned u; } v; v.f = x;
    unsigned r = v.u + 0x7fffu + ((v.u >> 16) & 1u);   // round-to-nearest-even
    return (short)(r >> 16);
}

__device__ inline void gload_lds16(const void* g, void* l) {
    __builtin_amdgcn_global_load_lds(
        (const __attribute__((address_space(1))) void*)g,
        (__attribute__((address_space(3))) void*)l,
        16, 0, 0);
}

// ---------------------------------------------------------------------------
// Kernel 1: pooling.  Block = 256 thr (4 waves) = 4 persons of one sequence.
// Phase A: stage sequence h (64x64 f32) + pos in LDS.
// Phase B: lane j computes cell(i,j); LDS atomicOr builds per-cell bitmask.
// Phase C: per cell, walk mask bits (sum in fp32), store bf16 row.
// Cell math bit-identical to jnp reference ((x/2)*8 == x*4 exactly in fp32).
// ---------------------------------------------------------------------------
__global__ __launch_bounds__(256) void pool_kernel(
    const float* __restrict__ h,     // (B, 64)
    const float* __restrict__ pos,   // (B, 2)
    short* __restrict__ pooled)      // (B, 4096) bf16
{
    __shared__ float hs[64 * 64];                 // 16 KB
    __shared__ float px[64], py[64];
    __shared__ unsigned long long wmask[4][64];   // 2 KB

    const int tid  = threadIdx.x;
    const int lane = tid & 63;
    const int w    = tid >> 6;
    const int s    = blockIdx.x >> 4;      // sequence
    const int grp  = blockIdx.x & 15;      // person group (4 persons)
    const size_t base = (size_t)s * 64;

    // stage h rows of this sequence (4096 floats) as float4
    const float4* hv  = (const float4*)(h + base * 64);
    float4*       hsv = (float4*)hs;
    #pragma unroll
    for (int c = 0; c < 4; ++c) hsv[tid + c * 256] = hv[tid + c * 256];
    if (tid < 64) {
        float2 p = ((const float2*)pos)[base + tid];
        px[tid] = p.x; py[tid] = p.y;
    }
    wmask[w][lane] = 0ull;
    __syncthreads();

    const int i = grp * 4 + w;             // this wave's person
    const float tlx = px[i] - 1.0f;
    const float tly = py[i] + 1.0f;
    const float brx = px[i] + 1.0f;
    const float bry = py[i] - 1.0f;

    {   // lane j: which cell does neighbor j fall in? (wave-local, no barrier)
        const int j = lane;
        const float ox = px[j], oy = py[j];
        if (ox < brx && ox > tlx && oy < tly && oy > bry && j != i) {
            int cx = (int)floorf((ox - tlx) * 4.0f);
            int cy = (int)floorf((tly - oy) * 4.0f);
            atomicOr(&wmask[w][cx + cy * 8], 1ull << j);
        }
    }

    const int d = lane;
    const size_t orow = (base + i) * 4096;
    for (int c = 0; c < 64; ++c) {
        unsigned long long m = wmask[w][c];
        float a0 = 0.f, a1 = 0.f;
        while (m) {
            int j0 = __builtin_ctzll(m); m &= m - 1;
            if (m) {
                int j1 = __builtin_ctzll(m); m &= m - 1;
                a1 += hs[j1 * 64 + d];
            }
            a0 += hs[j0 * 64 + d];
        }
        pooled[orow + c * 64 + d] = f2bf(a0 + a1);
    }
}

// ---------------------------------------------------------------------------
// Kernel 2: W (K x N fp32) -> Wt (N x K bf16).  64x64 tiles, float4 reads,
// short4 packed writes.
// ---------------------------------------------------------------------------
__global__ __launch_bounds__(256) void castWt_kernel(
    const float* __restrict__ W, short* __restrict__ Wt, int K, int N)
{
    __shared__ float t[64][65];
    const int tid = threadIdx.x;
    const int k0 = blockIdx.x * 64;
    const int n0 = blockIdx.y * 64;

    const int r  = tid >> 4;            // 0..15
    const int cq = (tid & 15) * 4;
    #pragma unroll
    for (int i = 0; i < 4; ++i) {
        const int row = r + i * 16;
        float4 v = *(const float4*)&W[(size_t)(k0 + row) * N + n0 + cq];
        t[row][cq + 0] = v.x; t[row][cq + 1] = v.y;
        t[row][cq + 2] = v.z; t[row][cq + 3] = v.w;
    }
    __syncthreads();
    const int nl = tid >> 4;
    const int kq = (tid & 15) * 4;
    #pragma unroll
    for (int i = 0; i < 4; ++i) {
        const int n = nl + i * 16;
        short4v o;
        o.x = f2bf(t[kq + 0][n]); o.y = f2bf(t[kq + 1][n]);
        o.z = f2bf(t[kq + 2][n]); o.w = f2bf(t[kq + 3][n]);
        *(short4v*)&Wt[(size_t)(n0 + n) * K + k0 + kq] = o;
    }
}

// ---------------------------------------------------------------------------
// Kernel 3: C = relu(A @ Bt^T + bias).  A: MxK bf16, Bt: NxK bf16.
// 128x64 block tile, BK=128, 4 waves (2x2), each wave 64x32 (4x2 MFMA tiles).
// global_load_lds(16B) staging; XOR swizzle (global side: slot ^ (row&15),
// read side: (4t+q) ^ ml) keeps ds_read_b128 conflict-free (0 measured in R0).
// ---------------------------------------------------------------------------
__global__ __launch_bounds__(256) void gemm_bias_relu(
    const short* __restrict__ A,
    const short* __restrict__ Bt,
    const float* __restrict__ bias,
    float* __restrict__ out,
    int M, int N, int K)
{
    __shared__ __align__(16) short As[BM * BK];  // 32 KB
    __shared__ __align__(16) short Bs[BN * BK];  // 16 KB

    const int tid  = threadIdx.x;
    const int lane = tid & 63;
    const int wave = tid >> 6;
    const int wr = wave >> 1;          // wave row (m): 0..1
    const int wc = wave & 1;           // wave col (n): 0..1
    const int q  = lane >> 4;          // quad 0..3
    const int ml = lane & 15;
    const int m0 = blockIdx.y * BM;
    const int n0 = blockIdx.x * BN;

    const int r4   = lane >> 4;        // row within 4-row staging group
    const int slot = lane & 15;        // 16B-granule slot within 256B row

    // per-thread staging pointers (advance BK shorts per K-iter)
    const short* ag[8];
    const short* bg[4];
    #pragma unroll
    for (int c = 0; c < 8; ++c) {
        const int gi = c * 4 + wave;           // 4-row group 0..31
        const int rl = gi * 4 + r4;            // local row 0..127
        ag[c] = A + (size_t)(m0 + rl) * K + (slot ^ (rl & 15)) * 8;
    }
    #pragma unroll
    for (int c = 0; c < 4; ++c) {
        const int gi = c * 4 + wave;           // 0..15
        const int rl = gi * 4 + r4;            // 0..63
        bg[c] = Bt + (size_t)(n0 + rl) * K + (slot ^ (rl & 15)) * 8;
    }

    floatx4 acc[4][2];
    #pragma unroll
    for (int i = 0; i < 4; ++i)
        #pragma unroll
        for (int j = 0; j < 2; ++j)
            acc[i][j] = (floatx4){0.f, 0.f, 0.f, 0.f};

    for (int kb = 0; kb < K; kb += BK) {
        if (kb) __syncthreads();
        #pragma unroll
        for (int c = 0; c < 8; ++c) {
            gload_lds16(ag[c], &As[(c * 4 + wave) * 512]);
            ag[c] += BK;
        }
        #pragma unroll
        for (int c = 0; c < 4; ++c) {
            gload_lds16(bg[c], &Bs[(c * 4 + wave) * 512]);
            bg[c] += BK;
        }
        __syncthreads();

        #pragma unroll
        for (int t = 0; t < 4; ++t) {
            short8 af[4], bf[2];
            const int gx = ((t * 4 + q) ^ ml) * 8;   // swizzled granule (shorts)
            #pragma unroll
            for (int i = 0; i < 4; ++i)
                af[i] = *(const short8*)&As[(wr * 64 + i * 16 + ml) * BK + gx];
            #pragma unroll
            for (int j = 0; j < 2; ++j)
                bf[j] = *(const short8*)&Bs[(wc * 32 + j * 16 + ml) * BK + gx];
            #pragma unroll
            for (int i = 0; i < 4; ++i)
                #pragma unroll
                for (int j = 0; j < 2; ++j)
                    acc[i][j] = __builtin_amdgcn_mfma_f32_16x16x32_bf16(
                        af[i], bf[j], acc[i][j], 0, 0, 0);
        }
    }

    // epilogue: bias + relu, fp32 store.  C/D layout: col=lane&15, row=q*4+reg.
    #pragma unroll
    for (int j = 0; j < 2; ++j) {
        const int gn = n0 + wc * 32 + j * 16 + ml;
        const float bv = bias[gn];
        #pragma unroll
        for (int i = 0; i < 4; ++i) {
            const int gm = m0 + wr * 64 + i * 16 + q * 4;
            #pragma unroll
            for (int r = 0; r < 4; ++r) {
                float v = acc[i][j][r] + bv;
                out[(size_t)(gm + r) * N + gn] = v > 0.f ? v : 0.f;
            }
        }
    }
}

// ---------------------------------------------------------------------------
extern "C" void kernel_launch(void* const* d_in, const int* in_sizes, int n_in,
                              void* d_out, int out_size, void* d_ws, size_t ws_size,
                              hipStream_t stream) {
    const float* h    = (const float*)d_in[0];   // (1, B, 64) f32
    const float* pos  = (const float*)d_in[2];   // (B, 2)     f32
    const float* W    = (const float*)d_in[4];   // (K, N)     f32
    const float* bias = (const float*)d_in[5];   // (N,)       f32

    const int B = in_sizes[0] / 64;       // 4096
    const int S = in_sizes[1] / 2;        // 64
    const int N = in_sizes[5];            // 1024
    const int K = 64 * 64;                // GRID^2 * H_DIM = 4096
    (void)S;

    short* pooled = (short*)d_ws;                  // B*K bf16 = 32 MB
    short* Wt     = pooled + (size_t)B * K;        // N*K bf16 =  8 MB
    float* out    = (float*)d_out;

    pool_kernel<<<B / 4, 256, 0, stream>>>(h, pos, pooled);
    castWt_kernel<<<dim3(K / 64, N / 64), 256, 0, stream>>>(W, Wt, K, N);
    gemm_bias_relu<<<dim3(N / BN, B / BM), 256, 0, stream>>>(pooled, Wt, bias, out, B, N, K);
}

// Round 3
// 141.013 us; speedup vs baseline: 1.1266x; 1.0022x over previous
//
#include <hip/hip_runtime.h>

// ---------------------------------------------------------------------------
// SocialPooling: pooled = per-person 8x8-grid scatter-add of neighbor hiddens,
// out = relu(pooled @ W + b).  M=B=4096, K=4096, N=1024.
// R3: GEMM restructured -- 128x128 tile, 8 waves (2 K-groups x 2x2 of 64x64),
// double-buffered LDS (BK=64, one barrier/iter, drain overlapped), LDS-based
// K-group reduce.  pool+castWt merged into one concurrent kernel.
// ---------------------------------------------------------------------------

#define BM 128
#define BN 128
#define BK 64    // shorts (bf16) per K-block per buffer

typedef short short8 __attribute__((ext_vector_type(8)));
typedef short short4v __attribute__((ext_vector_type(4)));
typedef float floatx4 __attribute__((ext_vector_type(4)));

__device__ inline short f2bf(float x) {
    union { float f; unsigned u; } v; v.f = x;
    unsigned r = v.u + 0x7fffu + ((v.u >> 16) & 1u);   // round-to-nearest-even
    return (short)(r >> 16);
}

__device__ inline void gload_lds16(const void* g, void* l) {
    __builtin_amdgcn_global_load_lds(
        (const __attribute__((address_space(1))) void*)g,
        (__attribute__((address_space(3))) void*)l,
        16, 0, 0);
}

// ---------------------------------------------------------------------------
// Kernel 1: prep = pool (blocks 0..1023) + W transpose/cast (blocks 1024..2047)
// merged so the two independent stages run concurrently.
// ---------------------------------------------------------------------------
__global__ __launch_bounds__(256) void prep_kernel(
    const float* __restrict__ h,     // (B, 64)
    const float* __restrict__ pos,   // (B, 2)
    short* __restrict__ pooled,      // (B, 4096) bf16
    const float* __restrict__ W,     // (K, N)
    short* __restrict__ Wt,          // (N, K) bf16
    int K, int N, int poolBlocks)
{
    __shared__ __align__(16) unsigned char sh[18944];
    const int tid = threadIdx.x;

    if ((int)blockIdx.x < poolBlocks) {
        // ----- pooling: 4 persons of one sequence per block -----
        float* hs = (float*)sh;                          // 64*64 f32 = 16 KB
        float* px = (float*)(sh + 16384);                // 64 f32
        float* py = (float*)(sh + 16640);                // 64 f32
        unsigned long long* wmask = (unsigned long long*)(sh + 16896); // 4*64

        const int lane = tid & 63;
        const int w    = tid >> 6;
        const int s    = blockIdx.x >> 4;
        const int grp  = blockIdx.x & 15;
        const size_t base = (size_t)s * 64;

        const float4* hv  = (const float4*)(h + base * 64);
        float4*       hsv = (float4*)hs;
        #pragma unroll
        for (int c = 0; c < 4; ++c) hsv[tid + c * 256] = hv[tid + c * 256];
        if (tid < 64) {
            float2 p = ((const float2*)pos)[base + tid];
            px[tid] = p.x; py[tid] = p.y;
        }
        wmask[w * 64 + lane] = 0ull;
        __syncthreads();

        const int i = grp * 4 + w;
        const float tlx = px[i] - 1.0f;
        const float tly = py[i] + 1.0f;
        const float brx = px[i] + 1.0f;
        const float bry = py[i] - 1.0f;

        {   // lane j: neighbor j's cell for person i (wave-local)
            const int j = lane;
            const float ox = px[j], oy = py[j];
            if (ox < brx && ox > tlx && oy < tly && oy > bry && j != i) {
                int cx = (int)floorf((ox - tlx) * 4.0f);
                int cy = (int)floorf((tly - oy) * 4.0f);
                atomicOr(&wmask[w * 64 + cx + cy * 8], 1ull << j);
            }
        }
        __builtin_amdgcn_s_waitcnt(0);  // LDS atomics within wave are ordered anyway

        const int d = lane;
        const size_t orow = (base + i) * 4096;
        for (int c = 0; c < 64; ++c) {
            unsigned long long m = wmask[w * 64 + c];
            float a0 = 0.f, a1 = 0.f;
            while (m) {
                int j0 = __builtin_ctzll(m); m &= m - 1;
                if (m) {
                    int j1 = __builtin_ctzll(m); m &= m - 1;
                    a1 += hs[j1 * 64 + d];
                }
                a0 += hs[j0 * 64 + d];
            }
            pooled[orow + c * 64 + d] = f2bf(a0 + a1);
        }
    } else {
        // ----- W (K x N f32) -> Wt (N x K bf16), 64x64 tiles -----
        float* t = (float*)sh;                 // [64][65] = 16.25 KB
        const int bid = blockIdx.x - poolBlocks;
        const int k0 = (bid & 63) * 64;        // K/64 = 64 tiles
        const int n0 = (bid >> 6) * 64;        // N/64 = 16 tiles

        const int r  = tid >> 4;               // 0..15
        const int cq = (tid & 15) * 4;
        #pragma unroll
        for (int i2 = 0; i2 < 4; ++i2) {
            const int row = r + i2 * 16;
            float4 v = *(const float4*)&W[(size_t)(k0 + row) * N + n0 + cq];
            t[row * 65 + cq + 0] = v.x; t[row * 65 + cq + 1] = v.y;
            t[row * 65 + cq + 2] = v.z; t[row * 65 + cq + 3] = v.w;
        }
        __syncthreads();
        const int nl = tid >> 4;
        const int kq = (tid & 15) * 4;
        #pragma unroll
        for (int i2 = 0; i2 < 4; ++i2) {
            const int n = nl + i2 * 16;
            short4v o;
            o.x = f2bf(t[(kq + 0) * 65 + n]); o.y = f2bf(t[(kq + 1) * 65 + n]);
            o.z = f2bf(t[(kq + 2) * 65 + n]); o.w = f2bf(t[(kq + 3) * 65 + n]);
            *(short4v*)&Wt[(size_t)(n0 + n) * K + k0 + kq] = o;
        }
    }
}

// ---------------------------------------------------------------------------
// Kernel 2: C = relu(A @ Bt^T + bias).  A: MxK bf16, Bt: NxK bf16.
// 128x128 block, 512 thr = 8 waves: kg = wave>>2 splits K; 2x2 waves of
// 64x64 (4x4 MFMA tiles).  Double-buffered LDS (BK=64): one barrier per
// K-iter, staging drain overlaps compute.  K-group reduce through LDS.
// ---------------------------------------------------------------------------
__global__ __launch_bounds__(512, 2) void gemm_bias_relu(
    const short* __restrict__ A,
    const short* __restrict__ Bt,
    const float* __restrict__ bias,
    float* __restrict__ out,
    int M, int N, int K)
{
    // [buf][mat][128 rows * 64 shorts] = 2*2*16 KB = 64 KB
    __shared__ __align__(16) short smem[2][2][BM * BK];

    const int tid  = threadIdx.x;
    const int lane = tid & 63;
    const int wave = tid >> 6;          // 0..7
    const int kg = wave >> 2;           // K-group 0..1
    const int w4 = wave & 3;
    const int wr = w4 >> 1;             // wave row in 2x2
    const int wc = w4 & 1;              // wave col
    const int q  = lane >> 4;           // quad 0..3
    const int ml = lane & 15;
    const int m0 = blockIdx.y * BM;
    const int n0 = blockIdx.x * BN;

    // staging: wave-issue covers 8 rows x 128B; lane = (r8, slot3)
    const int r8    = lane >> 3;        // 0..7
    const int slot3 = lane & 7;         // granule slot within 128B row

    // A: 16 groups of 8 rows; wave handles groups {wave, wave+8}. B same.
    const short* ag[2];
    const short* bg[2];
    int agrp[2];
    #pragma unroll
    for (int c = 0; c < 2; ++c) {
        const int g  = c * 8 + wave;            // 0..15
        const int rl = g * 8 + r8;              // 0..127
        agrp[c] = g;
        ag[c] = A  + (size_t)(m0 + rl) * K + (slot3 ^ (rl & 7)) * 8;
        bg[c] = Bt + (size_t)(n0 + rl) * K + (slot3 ^ (rl & 7)) * 8;
    }

    floatx4 acc[4][4];
    #pragma unroll
    for (int i = 0; i < 4; ++i)
        #pragma unroll
        for (int j = 0; j < 4; ++j)
            acc[i][j] = (floatx4){0.f, 0.f, 0.f, 0.f};

    // prologue: stage first K-block into buf 0
    #pragma unroll
    for (int c = 0; c < 2; ++c) {
        gload_lds16(ag[c], &smem[0][0][agrp[c] * 512]);
        gload_lds16(bg[c], &smem[0][1][agrp[c] * 512]);
        ag[c] += BK; bg[c] += BK;
    }
    __syncthreads();

    int buf = 0;
    const int gxg = ((kg * 4 + q) ^ (ml & 7)) * 8;  // read granule (shorts)
    for (int kb = 0; kb < K; kb += BK) {
        if (kb + BK < K) {                   // prefetch next block into buf^1
            #pragma unroll
            for (int c = 0; c < 2; ++c) {
                gload_lds16(ag[c], &smem[buf ^ 1][0][agrp[c] * 512]);
                gload_lds16(bg[c], &smem[buf ^ 1][1][agrp[c] * 512]);
                ag[c] += BK; bg[c] += BK;
            }
        }
        // compute on buf (this wave's K-slice: kg*32 .. kg*32+31)
        short8 af[4], bf[4];
        #pragma unroll
        for (int i = 0; i < 4; ++i)
            af[i] = *(const short8*)&smem[buf][0][(wr * 64 + i * 16 + ml) * BK + gxg];
        #pragma unroll
        for (int j = 0; j < 4; ++j)
            bf[j] = *(const short8*)&smem[buf][1][(wc * 64 + j * 16 + ml) * BK + gxg];
        #pragma unroll
        for (int i = 0; i < 4; ++i)
            #pragma unroll
            for (int j = 0; j < 4; ++j)
                acc[i][j] = __builtin_amdgcn_mfma_f32_16x16x32_bf16(
                    af[i], bf[j], acc[i][j], 0, 0, 0);

        __syncthreads();   // drains prefetch (overlapped w/ compute) + guards buf reuse
        buf ^= 1;
    }

    // K-group reduce through LDS (reuse smem as 4 x 16 KB fp32 regions).
    float* xp = (float*)smem + w4 * 4096;   // pair region, 64x64 fp32
    if (kg == 1) {
        #pragma unroll
        for (int i = 0; i < 4; ++i)
            #pragma unroll
            for (int j = 0; j < 4; ++j)
                #pragma unroll
                for (int r = 0; r < 4; ++r) {
                    const int row = i * 16 + q * 4 + r;
                    const int col = (j * 16 + ml + q * 8) & 63;  // 2-way = free
                    xp[row * 64 + col] = acc[i][j][r];
                }
    }
    __syncthreads();
    if (kg == 0) {
        #pragma unroll
        for (int j = 0; j < 4; ++j) {
            const int gn = n0 + wc * 64 + j * 16 + ml;
            const float bv = bias[gn];
            #pragma unroll
            for (int i = 0; i < 4; ++i)
                #pragma unroll
                for (int r = 0; r < 4; ++r) {
                    const int row = i * 16 + q * 4 + r;
                    const int col = (j * 16 + ml + q * 8) & 63;
                    float v = acc[i][j][r] + xp[row * 64 + col] + bv;
                    out[(size_t)(m0 + wr * 64 + row) * N + gn] = v > 0.f ? v : 0.f;
                }
        }
    }
}

// ---------------------------------------------------------------------------
extern "C" void kernel_launch(void* const* d_in, const int* in_sizes, int n_in,
                              void* d_out, int out_size, void* d_ws, size_t ws_size,
                              hipStream_t stream) {
    const float* h    = (const float*)d_in[0];   // (1, B, 64) f32
    const float* pos  = (const float*)d_in[2];   // (B, 2)     f32
    const float* W    = (const float*)d_in[4];   // (K, N)     f32
    const float* bias = (const float*)d_in[5];   // (N,)       f32

    const int B = in_sizes[0] / 64;       // 4096
    const int N = in_sizes[5];            // 1024
    const int K = 64 * 64;                // GRID^2 * H_DIM = 4096

    short* pooled = (short*)d_ws;                  // B*K bf16 = 32 MB
    short* Wt     = pooled + (size_t)B * K;        // N*K bf16 =  8 MB
    float* out    = (float*)d_out;

    const int poolBlocks = B / 4;                  // 1024
    const int castBlocks = (K / 64) * (N / 64);    // 1024
    prep_kernel<<<poolBlocks + castBlocks, 256, 0, stream>>>(
        h, pos, pooled, W, Wt, K, N, poolBlocks);
    gemm_bias_relu<<<dim3(N / BN, B / BM), 512, 0, stream>>>(
        pooled, Wt, bias, out, B, N, K);
}

// Round 4
// 133.258 us; speedup vs baseline: 1.1921x; 1.0582x over previous
//
#include <hip/hip_runtime.h>

// ---------------------------------------------------------------------------
// SocialPooling: pooled = per-person 8x8-grid scatter-add of neighbor hiddens,
// out = relu(pooled @ W + b).  M=B=4096, K=4096, N=1024.
// R4: revert to R2's proven single-buffer 2-barrier K-loop (dbuf was neutral,
// m99/m100-style), switch to 32x32x16 MFMA (half the MFMA instrs, +15% rate),
// XCD-clustered block swizzle for A-tile L2 reuse.  prep unchanged.
// ---------------------------------------------------------------------------

#define BM 128
#define BN 64
#define BK 128   // shorts (bf16) per K-block

typedef short short8 __attribute__((ext_vector_type(8)));
typedef short short4v __attribute__((ext_vector_type(4)));
typedef float floatx16 __attribute__((ext_vector_type(16)));

__device__ inline short f2bf(float x) {
    union { float f; unsigned u; } v; v.f = x;
    unsigned r = v.u + 0x7fffu + ((v.u >> 16) & 1u);   // round-to-nearest-even
    return (short)(r >> 16);
}

__device__ inline void gload_lds16(const void* g, void* l) {
    __builtin_amdgcn_global_load_lds(
        (const __attribute__((address_space(1))) void*)g,
        (__attribute__((address_space(3))) void*)l,
        16, 0, 0);
}

// ---------------------------------------------------------------------------
// Kernel 1: prep = pool (blocks 0..1023) + W transpose/cast (blocks 1024..2047)
// merged so the two independent stages run concurrently.
// ---------------------------------------------------------------------------
__global__ __launch_bounds__(256) void prep_kernel(
    const float* __restrict__ h,     // (B, 64)
    const float* __restrict__ pos,   // (B, 2)
    short* __restrict__ pooled,      // (B, 4096) bf16
    const float* __restrict__ W,     // (K, N)
    short* __restrict__ Wt,          // (N, K) bf16
    int K, int N, int poolBlocks)
{
    __shared__ __align__(16) unsigned char sh[18944];
    const int tid = threadIdx.x;

    if ((int)blockIdx.x < poolBlocks) {
        // ----- pooling: 4 persons of one sequence per block -----
        float* hs = (float*)sh;                          // 64*64 f32 = 16 KB
        float* px = (float*)(sh + 16384);
        float* py = (float*)(sh + 16640);
        unsigned long long* wmask = (unsigned long long*)(sh + 16896); // 4*64

        const int lane = tid & 63;
        const int w    = tid >> 6;
        const int s    = blockIdx.x >> 4;
        const int grp  = blockIdx.x & 15;
        const size_t base = (size_t)s * 64;

        const float4* hv  = (const float4*)(h + base * 64);
        float4*       hsv = (float4*)hs;
        #pragma unroll
        for (int c = 0; c < 4; ++c) hsv[tid + c * 256] = hv[tid + c * 256];
        if (tid < 64) {
            float2 p = ((const float2*)pos)[base + tid];
            px[tid] = p.x; py[tid] = p.y;
        }
        wmask[w * 64 + lane] = 0ull;
        __syncthreads();

        const int i = grp * 4 + w;
        const float tlx = px[i] - 1.0f;
        const float tly = py[i] + 1.0f;
        const float brx = px[i] + 1.0f;
        const float bry = py[i] - 1.0f;

        {   // lane j: neighbor j's cell for person i (wave-local)
            const int j = lane;
            const float ox = px[j], oy = py[j];
            if (ox < brx && ox > tlx && oy < tly && oy > bry && j != i) {
                int cx = (int)floorf((ox - tlx) * 4.0f);
                int cy = (int)floorf((tly - oy) * 4.0f);
                atomicOr(&wmask[w * 64 + cx + cy * 8], 1ull << j);
            }
        }

        const int d = lane;
        const size_t orow = (base + i) * 4096;
        for (int c = 0; c < 64; ++c) {
            unsigned long long m = wmask[w * 64 + c];
            float a0 = 0.f, a1 = 0.f;
            while (m) {
                int j0 = __builtin_ctzll(m); m &= m - 1;
                if (m) {
                    int j1 = __builtin_ctzll(m); m &= m - 1;
                    a1 += hs[j1 * 64 + d];
                }
                a0 += hs[j0 * 64 + d];
            }
            pooled[orow + c * 64 + d] = f2bf(a0 + a1);
        }
    } else {
        // ----- W (K x N f32) -> Wt (N x K bf16), 64x64 tiles -----
        float* t = (float*)sh;                 // [64][65]
        const int bid = blockIdx.x - poolBlocks;
        const int k0 = (bid & 63) * 64;
        const int n0 = (bid >> 6) * 64;

        const int r  = tid >> 4;               // 0..15
        const int cq = (tid & 15) * 4;
        #pragma unroll
        for (int i2 = 0; i2 < 4; ++i2) {
            const int row = r + i2 * 16;
            float4 v = *(const float4*)&W[(size_t)(k0 + row) * N + n0 + cq];
            t[row * 65 + cq + 0] = v.x; t[row * 65 + cq + 1] = v.y;
            t[row * 65 + cq + 2] = v.z; t[row * 65 + cq + 3] = v.w;
        }
        __syncthreads();
        const int nl = tid >> 4;
        const int kq = (tid & 15) * 4;
        #pragma unroll
        for (int i2 = 0; i2 < 4; ++i2) {
            const int n = nl + i2 * 16;
            short4v o;
            o.x = f2bf(t[(kq + 0) * 65 + n]); o.y = f2bf(t[(kq + 1) * 65 + n]);
            o.z = f2bf(t[(kq + 2) * 65 + n]); o.w = f2bf(t[(kq + 3) * 65 + n]);
            *(short4v*)&Wt[(size_t)(n0 + n) * K + k0 + kq] = o;
        }
    }
}

// ---------------------------------------------------------------------------
// Kernel 2: C = relu(A @ Bt^T + bias).  A: MxK bf16, Bt: NxK bf16.
// 128x64 block tile, BK=128, 4 waves (2x2), wave tile 64x32 = 2x1 of 32x32x16
// MFMA.  global_load_lds(16B) staging with XOR granule swizzle (R2-proven,
// 0 conflicts).  XCD-clustered block mapping: XCD x owns m-blocks 4x..4x+3,
// n iterates fastest -> A row-block reused 16x within one XCD's L2.
// ---------------------------------------------------------------------------
__global__ __launch_bounds__(256) void gemm_bias_relu(
    const short* __restrict__ A,
    const short* __restrict__ Bt,
    const float* __restrict__ bias,
    float* __restrict__ out,
    int M, int N, int K)
{
    __shared__ __align__(16) short As[BM * BK];  // 32 KB
    __shared__ __align__(16) short Bs[BN * BK];  // 16 KB

    const int tid  = threadIdx.x;
    const int lane = tid & 63;
    const int wave = tid >> 6;
    const int wr = wave >> 1;          // wave row (m): 0..1
    const int wc = wave & 1;           // wave col (n): 0..1
    const int nl = lane & 31;          // MFMA row/col within 32
    const int hl = lane >> 5;          // K-half
    const int ml = lane & 15;          // swizzle key (= row&15 of frag rows)

    // XCD-clustered mapping (dispatch: block b -> XCD b%8)
    const int b  = blockIdx.x;
    const int ib = b >> 3;
    const int m0 = ((b & 7) * 4 + (ib >> 4)) * BM;
    const int n0 = (ib & 15) * BN;

    const int r4   = lane >> 4;        // row within 4-row staging group
    const int slot = lane & 15;        // 16B-granule slot within 256B row

    const short* ag[8];
    const short* bg[4];
    #pragma unroll
    for (int c = 0; c < 8; ++c) {
        const int gi = c * 4 + wave;           // 0..31
        const int rl = gi * 4 + r4;            // 0..127
        ag[c] = A + (size_t)(m0 + rl) * K + (slot ^ (rl & 15)) * 8;
    }
    #pragma unroll
    for (int c = 0; c < 4; ++c) {
        const int gi = c * 4 + wave;           // 0..15
        const int rl = gi * 4 + r4;            // 0..63
        bg[c] = Bt + (size_t)(n0 + rl) * K + (slot ^ (rl & 15)) * 8;
    }

    floatx16 acc[2];
    #pragma unroll
    for (int mt = 0; mt < 2; ++mt)
        #pragma unroll
        for (int r = 0; r < 16; ++r) acc[mt][r] = 0.f;

    for (int kb = 0; kb < K; kb += BK) {
        if (kb) __syncthreads();
        #pragma unroll
        for (int c = 0; c < 8; ++c) {
            gload_lds16(ag[c], &As[(c * 4 + wave) * 512]);
            ag[c] += BK;
        }
        #pragma unroll
        for (int c = 0; c < 4; ++c) {
            gload_lds16(bg[c], &Bs[(c * 4 + wave) * 512]);
            bg[c] += BK;
        }
        __syncthreads();

        #pragma unroll
        for (int t = 0; t < 8; ++t) {                  // 8 x K=16 steps
            const int g  = 2 * t + hl;                 // needed granule
            short8 a0 = *(const short8*)&As[(wr * 64 +      nl) * BK + ((g ^ ml) * 8)];
            short8 a1 = *(const short8*)&As[(wr * 64 + 32 + nl) * BK + ((g ^ ml) * 8)];
            short8 bfr = *(const short8*)&Bs[(wc * 32 +     nl) * BK + ((g ^ ml) * 8)];
            acc[0] = __builtin_amdgcn_mfma_f32_32x32x16_bf16(a0, bfr, acc[0], 0, 0, 0);
            acc[1] = __builtin_amdgcn_mfma_f32_32x32x16_bf16(a1, bfr, acc[1], 0, 0, 0);
        }
    }

    // epilogue: bias + relu.  32x32 C/D: col=lane&31, row=(r&3)+8*(r>>2)+4*hl.
    const int gn = n0 + wc * 32 + nl;
    const float bv = bias[gn];
    #pragma unroll
    for (int mt = 0; mt < 2; ++mt) {
        #pragma unroll
        for (int r = 0; r < 16; ++r) {
            const int row32 = (r & 3) + 8 * (r >> 2) + 4 * hl;
            const int gm = m0 + wr * 64 + mt * 32 + row32;
            float v = acc[mt][r] + bv;
            out[(size_t)gm * N + gn] = v > 0.f ? v : 0.f;
        }
    }
}

// ---------------------------------------------------------------------------
extern "C" void kernel_launch(void* const* d_in, const int* in_sizes, int n_in,
                              void* d_out, int out_size, void* d_ws, size_t ws_size,
                              hipStream_t stream) {
    const float* h    = (const float*)d_in[0];   // (1, B, 64) f32
    const float* pos  = (const float*)d_in[2];   // (B, 2)     f32
    const float* W    = (const float*)d_in[4];   // (K, N)     f32
    const float* bias = (const float*)d_in[5];   // (N,)       f32

    const int B = in_sizes[0] / 64;       // 4096
    const int N = in_sizes[5];            // 1024
    const int K = 64 * 64;                // GRID^2 * H_DIM = 4096

    short* pooled = (short*)d_ws;                  // B*K bf16 = 32 MB
    short* Wt     = pooled + (size_t)B * K;        // N*K bf16 =  8 MB
    float* out    = (float*)d_out;

    const int poolBlocks = B / 4;                  // 1024
    const int castBlocks = (K / 64) * (N / 64);    // 1024
    prep_kernel<<<poolBlocks + castBlocks, 256, 0, stream>>>(
        h, pos, pooled, W, Wt, K, N, poolBlocks);
    gemm_bias_relu<<<(B / BM) * (N / BN), 256, 0, stream>>>(
        pooled, Wt, bias, out, B, N, K);
}